// Round 3
// baseline (157.559 us; speedup 1.0000x reference)
//
#include <hip/hip_runtime.h>

// Problem constants (fixed by the reference)
#define NN   16
#define DD   3
#define HH   160
#define WW   160
#define MM   8
#define KK   10
#define PP   15
#define PM   7            // (P-1)/2
#define OUTH 146          // H - P + 1
#define OUTW 146
#define MK   (MM*KK)      // 80

// Block geometry
#define BY      10        // output rows per block
#define ROWS    23        // staged input rows per channel: BY-1 + sy_max(12) + 2 taps
#define NTILES  15        // ceil(146/10), last tile clamped (dup rows, bit-identical)
#define SGRP    4         // mk split: 4 groups of 20
#define MKG     20
#define THREADS 384       // 73 col-pairs x 5 row-groups = 365 active + 19 idle
#define CPW     73        // column-pairs across OUTW=146
#define RGRP    5         // row-groups of 2 rows -> BY=10
#define PLANE   (HH*WW)   // 25600
#define STAGE4  (DD*ROWS*(WW/4))  // 2760 float4 per block

typedef float vfloat2 __attribute__((ext_vector_type(2)));

__global__ __launch_bounds__(THREADS)
void fern_bits_kernel(const float* __restrict__ T,
                      const float* __restrict__ dx1,
                      const float* __restrict__ dx2,
                      const float* __restrict__ dy1,
                      const float* __restrict__ dy2,
                      const float* __restrict__ th,
                      const float* __restrict__ amb,
                      const int*   __restrict__ channels,
                      float* __restrict__ out)
{
    __shared__ float lds[DD * ROWS * WW];   // 3*23*160 floats = 44.16 KB

    const int tid = threadIdx.x;
    const int n   = blockIdx.z;                       // 0..15
    const int y0  = min((int)blockIdx.x * BY, OUTH - BY); // clamp: tile 14 dups rows 136..139

    // ---- Stage T[n, 0..2, y0 .. y0+22, :] into LDS (coalesced float4) ----
    const float* __restrict__ Tn = T + (size_t)n * DD * PLANE;
#pragma unroll 2
    for (int j = tid; j < STAGE4; j += THREADS) {
        const int c   = j / (ROWS * (WW/4));          // /920
        const int rem = j - c * (ROWS * (WW/4));
        const int r   = rem / (WW/4);                 // /40
        const int q   = rem - r * (WW/4);
        const float4 v = *(const float4*)(Tn + c * PLANE + (y0 + r) * WW + q * 4);
        *(float4*)&lds[(c * ROWS + r) * WW + q * 4] = v;
    }
    __syncthreads();

    // ---- Thread micro-tile: 2 cols x 2 rows ----
    const int cp = tid % CPW;          // 0..72
    const int rg = tid / CPW;          // 0..5 (5 = idle)
    const bool active = (rg < RGRP);
    const int xo  = cp * 2;            // even output column
    const int ro0 = rg * 2;            // local output row base (0..8)

    // Output base for this thread (row y0+ro0, col xo) — advances by plane per mk
    float* __restrict__ obase =
        out + ((size_t)(n * MK + blockIdx.y * MKG) * OUTH + (y0 + ro0)) * OUTW + xo;

    for (int g = 0; g < MKG; ++g) {
        const int mk = blockIdx.y * MKG + g;
        const int k  = mk % KK;
        const int m  = mk / KK;
        const int c  = channels[k];                 // block-uniform -> scalar

        float a, f;
        a = dx1[mk]; f = floorf(a); const float fx1 = a - f; const int sx1 = PM + (int)f;
        a = dy1[mk]; f = floorf(a); const float fy1 = a - f; const int sy1 = PM + (int)f;
        a = dx2[mk]; f = floorf(a); const float fx2 = a - f; const int sx2 = PM + (int)f;
        a = dy2[mk]; f = floorf(a); const float fy2 = a - f; const int sy2 = PM + (int)f;
        const float thv = th[mk];
        const float pos = amb[(m*2 + 0)*KK + k];
        const float neg = amb[(m*2 + 1)*KK + k];
        const float scl = 1.0f / (pos - neg + 1e-29f);

        if (active) {
            // ---- Sample 1: 3x3 taps from LDS, shared by the 2x2 outputs ----
            const int b1 = (c * ROWS + ro0 + sy1) * WW + xo + sx1;
            const float t00 = lds[b1      ], t01 = lds[b1 + 1      ], t02 = lds[b1 + 2      ];
            const float t10 = lds[b1 + WW ], t11 = lds[b1 + WW + 1 ], t12 = lds[b1 + WW + 2 ];
            const float t20 = lds[b1 + 2*WW], t21 = lds[b1 + 2*WW + 1], t22 = lds[b1 + 2*WW + 2];
            const float h00 = t00 + fx1 * (t01 - t00), h01 = t01 + fx1 * (t02 - t01);
            const float h10 = t10 + fx1 * (t11 - t10), h11 = t11 + fx1 * (t12 - t11);
            const float h20 = t20 + fx1 * (t21 - t20), h21 = t21 + fx1 * (t22 - t21);
            const float p1aa = h00 + fy1 * (h10 - h00);   // (ro0,   xo)
            const float p1ab = h01 + fy1 * (h11 - h01);   // (ro0,   xo+1)
            const float p1ba = h10 + fy1 * (h20 - h10);   // (ro0+1, xo)
            const float p1bb = h11 + fy1 * (h21 - h11);   // (ro0+1, xo+1)

            // ---- Sample 2 ----
            const int b2 = (c * ROWS + ro0 + sy2) * WW + xo + sx2;
            const float u00 = lds[b2      ], u01 = lds[b2 + 1      ], u02 = lds[b2 + 2      ];
            const float u10 = lds[b2 + WW ], u11 = lds[b2 + WW + 1 ], u12 = lds[b2 + WW + 2 ];
            const float u20 = lds[b2 + 2*WW], u21 = lds[b2 + 2*WW + 1], u22 = lds[b2 + 2*WW + 2];
            const float g00 = u00 + fx2 * (u01 - u00), g01 = u01 + fx2 * (u02 - u01);
            const float g10 = u10 + fx2 * (u11 - u10), g11 = u11 + fx2 * (u12 - u11);
            const float g20 = u20 + fx2 * (u21 - u20), g21 = u21 + fx2 * (u22 - u21);
            const float p2aa = g00 + fy2 * (g10 - g00);
            const float p2ab = g01 + fy2 * (g11 - g01);
            const float p2ba = g10 + fy2 * (g20 - g10);
            const float p2bb = g11 + fy2 * (g21 - g11);

            // ---- Epilogue: deadzone, threshold, clamp ----
            float daa = p1aa - p2aa; if (fabsf(daa) < 1e-5f) daa = 0.0f;
            float dab = p1ab - p2ab; if (fabsf(dab) < 1e-5f) dab = 0.0f;
            float dba = p1ba - p2ba; if (fabsf(dba) < 1e-5f) dba = 0.0f;
            float dbb = p1bb - p2bb; if (fabsf(dbb) < 1e-5f) dbb = 0.0f;
            const float oaa = __builtin_amdgcn_fmed3f((daa - thv - neg) * scl, 0.0f, 1.0f);
            const float oab = __builtin_amdgcn_fmed3f((dab - thv - neg) * scl, 0.0f, 1.0f);
            const float oba = __builtin_amdgcn_fmed3f((dba - thv - neg) * scl, 0.0f, 1.0f);
            const float obb = __builtin_amdgcn_fmed3f((dbb - thv - neg) * scl, 0.0f, 1.0f);

            // ---- Stores: 2x float2, coalesced (lanes stride 8B), nontemporal ----
            float* orow = obase + (size_t)g * (OUTH * OUTW);
            vfloat2 s;
            s.x = oaa; s.y = oab; __builtin_nontemporal_store(s, (vfloat2*)(orow));
            s.x = oba; s.y = obb; __builtin_nontemporal_store(s, (vfloat2*)(orow + OUTW));
        }
    }
}

extern "C" void kernel_launch(void* const* d_in, const int* in_sizes, int n_in,
                              void* d_out, int out_size, void* d_ws, size_t ws_size,
                              hipStream_t stream) {
    const float* T        = (const float*)d_in[0];
    const float* dx1      = (const float*)d_in[1];
    const float* dx2      = (const float*)d_in[2];
    const float* dy1      = (const float*)d_in[3];
    const float* dy2      = (const float*)d_in[4];
    const float* th       = (const float*)d_in[5];
    const float* amb      = (const float*)d_in[6];
    const int*   channels = (const int*)d_in[7];
    // d_in[8] = patch_size scalar (compile-time constant PP=15 here)
    float* out = (float*)d_out;

    dim3 grid(NTILES, SGRP, NN);     // 15 y-tiles x 4 mk-groups x 16 n = 960 blocks
    dim3 block(THREADS, 1, 1);
    fern_bits_kernel<<<grid, block, 0, stream>>>(T, dx1, dx2, dy1, dy2, th, amb,
                                                 channels, out);
}

// Round 4
// 151.740 us; speedup vs baseline: 1.0383x; 1.0383x over previous
//
#include <hip/hip_runtime.h>

// Problem constants (fixed by the reference)
#define NN   16
#define DD   3
#define HH   160
#define WW   160
#define MM   8
#define KK   10
#define PP   15
#define PM   7            // (P-1)/2
#define OUTH 146          // H - P + 1
#define OUTW 146
#define MK   (MM*KK)      // 80
#define YT   73           // row-pairs per plane (146/2)
#define XT   37           // col-quads per plane (ceil(146/4), last overlaps)
#define UNITS (YT*XT)     // 2701 micro-tiles per (mk,n) plane

typedef float vfloat4 __attribute__((ext_vector_type(4)));

__global__ __launch_bounds__(256)
void fern_bits_kernel(const float* __restrict__ T,
                      const float* __restrict__ dx1,
                      const float* __restrict__ dx2,
                      const float* __restrict__ dy1,
                      const float* __restrict__ dy2,
                      const float* __restrict__ th,
                      const float* __restrict__ amb,
                      const int*   __restrict__ channels,
                      float* __restrict__ out)
{
    const int mk = blockIdx.y;       // 0..79
    const int n  = blockIdx.z;       // 0..15
    const int k  = mk % KK;
    const int m  = mk / KK;
    const int c  = channels[k];

    // Per-feature (block-uniform) parameters — compile to scalar loads
    float a, f;
    a = dx1[mk]; f = floorf(a); const float fx1 = a - f; const int sx1 = PM + (int)f;
    a = dy1[mk]; f = floorf(a); const float fy1 = a - f; const int sy1 = PM + (int)f;
    a = dx2[mk]; f = floorf(a); const float fx2 = a - f; const int sx2 = PM + (int)f;
    a = dy2[mk]; f = floorf(a); const float fy2 = a - f; const int sy2 = PM + (int)f;
    const float thv = th[mk];
    const float pos = amb[(m*2 + 0)*KK + k];
    const float neg = amb[(m*2 + 1)*KK + k];
    const float scl = 1.0f / (pos - neg + 1e-29f);

    const float* __restrict__ Tp = T + (size_t)(n*DD + c) * (HH*WW);

    const int u = blockIdx.x * 256 + threadIdx.x;
    if (u >= UNITS) return;
    const int ty = u / XT;               // 0..72  (row-pair index)
    const int tx = u - ty * XT;          // 0..36  (col-quad index)
    const int y  = ty * 2;
    int x = tx * 4;
    if (x > OUTW - 4) x = OUTW - 4;      // tail: overlap-recompute cols 142..145 (bit-identical dup stores)

    // Sample bases; sample-2 offset from sample-1 is block-uniform
    const float* r1 = Tp + (sy1 + y) * WW + (sx1 + x);
    const float* r2 = Tp + (sy2 + y) * WW + (sx2 + x);

    // Issue all 30 loads up front (immediate offsets, 2 base addrs) for max MLP
    float v1v[3][5], v2v[3][5];
#pragma unroll
    for (int j = 0; j < 3; ++j) {
#pragma unroll
        for (int i = 0; i < 5; ++i) {
            v1v[j][i] = r1[j * WW + i];
            v2v[j][i] = r2[j * WW + i];
        }
    }

    // Horizontal lerps: one per input row, shared by both output rows
    float h1[3][4], h2[3][4];
#pragma unroll
    for (int j = 0; j < 3; ++j) {
#pragma unroll
        for (int i = 0; i < 4; ++i) {
            h1[j][i] = v1v[j][i] + fx1 * (v1v[j][i+1] - v1v[j][i]);
            h2[j][i] = v2v[j][i] + fx2 * (v2v[j][i+1] - v2v[j][i]);
        }
    }

    // Vertical lerps: row j is bottom of output-row 0 and top of output-row 1
    float q1a[4], q1b[4], q2a[4], q2b[4];
#pragma unroll
    for (int i = 0; i < 4; ++i) {
        q1a[i] = h1[0][i] + fy1 * (h1[1][i] - h1[0][i]);
        q1b[i] = h1[1][i] + fy1 * (h1[2][i] - h1[1][i]);
        q2a[i] = h2[0][i] + fy2 * (h2[1][i] - h2[0][i]);
        q2b[i] = h2[1][i] + fy2 * (h2[2][i] - h2[1][i]);
    }

    // Epilogue: deadzone, threshold, clamp (fmed3 = 1-instr clamp)
    vfloat4 s0, s1;
#pragma unroll
    for (int i = 0; i < 4; ++i) {
        float d0 = q1a[i] - q2a[i]; if (fabsf(d0) < 1e-5f) d0 = 0.0f;
        float d1 = q1b[i] - q2b[i]; if (fabsf(d1) < 1e-5f) d1 = 0.0f;
        s0[i] = __builtin_amdgcn_fmed3f((d0 - thv - neg) * scl, 0.0f, 1.0f);
        s1[i] = __builtin_amdgcn_fmed3f((d1 - thv - neg) * scl, 0.0f, 1.0f);
    }

    // Stores: 2x float4 (16B-aligned: x%4==0 except clamped tail at 8B — OK on gfx950),
    // nontemporal (109MB stream >> L2). Lanes stride 16B -> contiguous 1KB wave bursts.
    float* orow0 = out + ((size_t)(n * MK + mk) * OUTH + y) * OUTW + x;
    float* orow1 = orow0 + OUTW;
    __builtin_nontemporal_store(s0, (vfloat4*)(orow0));
    __builtin_nontemporal_store(s1, (vfloat4*)(orow1));
}

extern "C" void kernel_launch(void* const* d_in, const int* in_sizes, int n_in,
                              void* d_out, int out_size, void* d_ws, size_t ws_size,
                              hipStream_t stream) {
    const float* T        = (const float*)d_in[0];
    const float* dx1      = (const float*)d_in[1];
    const float* dx2      = (const float*)d_in[2];
    const float* dy1      = (const float*)d_in[3];
    const float* dy2      = (const float*)d_in[4];
    const float* th       = (const float*)d_in[5];
    const float* amb      = (const float*)d_in[6];
    const int*   channels = (const int*)d_in[7];
    // d_in[8] = patch_size scalar (compile-time constant PP=15 here)
    float* out = (float*)d_out;

    dim3 grid((UNITS + 255) / 256, MK, NN);
    dim3 block(256, 1, 1);
    fern_bits_kernel<<<grid, block, 0, stream>>>(T, dx1, dx2, dy1, dy2, th, amb,
                                                 channels, out);
}